// Round 8
// baseline (91.613 us; speedup 1.0000x reference)
//
#include <hip/hip_runtime.h>
#include <math.h>

#define B_  16
#define C_  2048
#define P_  16
#define CR_ 128

// ---------------------------------------------------------------------------
// Grid barrier, relaxed-spin version. R6's version spun on an ACQUIRE
// agent-scope load -> per-poll cache maintenance from 256 leaders = L2
// invalidate storm (~30us/barrier). Here: RELEASE add publishes our stores,
// RELAXED polls (plain coherent loads, no maintenance), then ONE acquire
// fence once the count is reached. Counters zeroed via hipMemsetAsync each
// launch; cooperative launch guarantees co-residency (no deadlock).
// ---------------------------------------------------------------------------
__device__ __forceinline__ void gbar(unsigned* ctr, unsigned nblk) {
    __syncthreads();
    if (threadIdx.x == 0) {
        __hip_atomic_fetch_add(ctr, 1u, __ATOMIC_RELEASE, __HIP_MEMORY_SCOPE_AGENT);
        while (__hip_atomic_load(ctr, __ATOMIC_RELAXED, __HIP_MEMORY_SCOPE_AGENT) < nblk)
            __builtin_amdgcn_s_sleep(8);
        __builtin_amdgcn_fence(__ATOMIC_ACQUIRE, "agent");
    }
    __syncthreads();
}

// ===================== Fused kernel =====================
// grid = 256 blocks x 512 threads, 1 block/CU, 64 KiB LDS.
// P1: patch means -> y.   [W1 loads issued]  gbar.
// P2: fc1+relu -> h2 (block-exclusive 512B regions).  [W2 loads issued]  gbar.
// P3: fc2+sigmoid -> out.
__global__ void __launch_bounds__(512, 2) k_fused(
    const float* __restrict__ x, const float* __restrict__ w1,
    const float* __restrict__ w2, float* __restrict__ out,
    float* __restrict__ y, float* __restrict__ h2, unsigned* __restrict__ bars)
{
    __shared__ float smem[16 * 1024];                 // 64 KiB
    float4* sm4 = reinterpret_cast<float4*>(smem);
    const int tid  = threadIdx.x;
    const int wib  = tid >> 6;
    const int lane = tid & 63;
    const int bid  = blockIdx.x;

    // ---------- Phase 1: y[b][c] = mean of x[b,c,16:32,16:32] ----------
    {
        const int wid = bid * 8 + wib;                // [0,2048), 16 patches/wave
        const int row = lane >> 2, col = (lane & 3) * 4;
        const float* base = x + (size_t)wid * 16 * 4096 + (16 * 64 + 16)
                          + row * 64 + col;
        #pragma unroll
        for (int g = 0; g < 2; ++g) {
            float s[8];
            #pragma unroll
            for (int j = 0; j < 8; ++j) {
                float4 v = *reinterpret_cast<const float4*>(base + (g * 8 + j) * 4096);
                s[j] = (v.x + v.y) + (v.z + v.w);
            }
            #pragma unroll
            for (int j = 0; j < 8; ++j) {
                #pragma unroll
                for (int m = 32; m >= 1; m >>= 1) s[j] += __shfl_xor(s[j], m, 64);
            }
            float v = s[0];
            v = (lane == 1) ? s[1] : v;
            v = (lane == 2) ? s[2] : v;
            v = (lane == 3) ? s[3] : v;
            v = (lane == 4) ? s[4] : v;
            v = (lane == 5) ? s[5] : v;
            v = (lane == 6) ? s[6] : v;
            v = (lane == 7) ? s[7] : v;
            if (lane < 8) y[wid * 16 + g * 8 + lane] = v * (1.0f / 256.0f);
        }
    }

    // ---------- Phase 2 W1 prefetch: issue BEFORE the barrier ----------
    const bool work = (wib < 4);                      // 4 working waves/block
    const int r0 = (bid * 4 + wib) * 2;               // rows r0, r0+1 (same p)
    const float4* w1v = reinterpret_cast<const float4*>(w1);
    const float4* wr0 = w1v + (size_t)r0 * 512;
    const float4* wr1 = wr0 + 512;
    float4 wA[8], wB[8];
    if (work) {
        #pragma unroll
        for (int i = 0; i < 8; ++i) wA[i] = wr0[i * 64 + lane];
        #pragma unroll
        for (int i = 0; i < 8; ++i) wB[i] = wr1[i * 64 + lane];
    }

    gbar(&bars[0], 256u);

    // ---------- Phase 2: h2 = relu(W1 . y) ----------
    {
        const float4* yv = reinterpret_cast<const float4*>(y);

        float acc0[16], acc1[16];
        #pragma unroll
        for (int b = 0; b < 16; ++b) { acc0[b] = 0.f; acc1[b] = 0.f; }

        #pragma unroll
        for (int pass = 0; pass < 2; ++pass) {
            // stage y[:, pass*1024 : +1024] as [16][256] float4
            #pragma unroll
            for (int i = 0; i < 8; ++i) {
                int f = i * 512 + tid;                // [0,4096)
                int b = f >> 8, c4 = f & 255;
                sm4[f] = yv[b * 512 + pass * 256 + c4];
            }
            __syncthreads();
            if (work) {
                #pragma unroll
                for (int il = 0; il < 4; ++il) {
                    float4 wa = wA[pass * 4 + il];
                    float4 wb = wB[pass * 4 + il];
                    #pragma unroll
                    for (int b = 0; b < 16; ++b) {
                        float4 v = sm4[b * 256 + il * 64 + lane];
                        acc0[b] += wa.x * v.x + wa.y * v.y + wa.z * v.z + wa.w * v.w;
                        acc1[b] += wb.x * v.x + wb.y * v.y + wb.z * v.z + wb.w * v.w;
                    }
                }
            }
            __syncthreads();
        }

        if (work) {
            #pragma unroll
            for (int b = 0; b < 16; ++b) {
                #pragma unroll
                for (int m = 32; m >= 1; m >>= 1) {
                    acc0[b] += __shfl_xor(acc0[b], m, 64);
                    acc1[b] += __shfl_xor(acc1[b], m, 64);
                }
            }
            float v0 = acc0[0], v1 = acc1[0];
            #pragma unroll
            for (int b = 1; b < 16; ++b) {
                v0 = (lane == b) ? acc0[b] : v0;
                v1 = (lane == b) ? acc1[b] : v1;
            }
            if (lane < 16) {
                // h2[p][m][b][k']: p=r0>>7, m=bid&15, b=lane, k'=2*wib (+1)
                const int p = r0 >> 7;
                const int idx = p * 2048 + (bid & 15) * 128 + lane * 8 + 2 * wib;
                h2[idx]     = fmaxf(v0, 0.f);
                h2[idx + 1] = fmaxf(v1, 0.f);
            }
        }
    }

    // ---------- Phase 3 W2 prefetch: issue BEFORE the barrier ----------
    const int p3p = bid >> 4;
    const int c0  = (bid & 15) * 128 + wib * 16;      // 16 c-rows per wave
    const int row3 = lane >> 2, q = lane & 3;
    const float4* wr = reinterpret_cast<const float4*>(w2)
                     + ((size_t)p3p * C_ + c0 + row3) * (CR_ / 4);
    float4 wv[8];
    #pragma unroll
    for (int j = 0; j < 8; ++j) wv[j] = wr[q + 4 * j];

    gbar(&bars[32], 256u);

    // ---------- Phase 3: out[p][b][c] = sigmoid(W2[p][c][:] . h[p][b][:]) ----------
    {
        const float4* hv = reinterpret_cast<const float4*>(h2);
        sm4[tid] = hv[p3p * 512 + tid];               // stage h2[p] (8 KiB)
        __syncthreads();

        float acc[16];
        #pragma unroll
        for (int b = 0; b < 16; ++b) acc[b] = 0.f;
        #pragma unroll
        for (int j = 0; j < 8; ++j) {
            const int k4 = q + 4 * j;                 // float4 index in k
            const int m  = k4 >> 1, kk = k4 & 1;      // h2 slice / half
            #pragma unroll
            for (int b = 0; b < 16; ++b) {
                float4 h4 = sm4[m * 32 + b * 2 + kk];
                acc[b] += wv[j].x * h4.x + wv[j].y * h4.y
                        + wv[j].z * h4.z + wv[j].w * h4.w;
            }
        }
        #pragma unroll
        for (int b = 0; b < 16; ++b) {
            acc[b] += __shfl_xor(acc[b], 1, 64);
            acc[b] += __shfl_xor(acc[b], 2, 64);
        }
        #pragma unroll
        for (int i = 0; i < 4; ++i) {
            float v = acc[i];
            v = (q == 1) ? acc[4 + i]  : v;
            v = (q == 2) ? acc[8 + i]  : v;
            v = (q == 3) ? acc[12 + i] : v;
            int b = q * 4 + i;
            out[(((size_t)p3p * B_ + b) << 11) + c0 + row3] = 1.0f / (1.0f + expf(-v));
        }
    }
}

// ===================== Fallback: R7 3-kernel path =====================
__global__ void __launch_bounds__(256) k_mean(const float* __restrict__ x,
                                              float* __restrict__ y) {
    int wave = blockIdx.x * (blockDim.x >> 6) + (threadIdx.x >> 6);
    int lane = threadIdx.x & 63;
    int row = lane >> 2, col = (lane & 3) * 4;
    const float* base = x + (size_t)wave * 8 * 4096 + (16 * 64 + 16) + row * 64 + col;
    float4 v[8];
    #pragma unroll
    for (int j = 0; j < 8; ++j)
        v[j] = *reinterpret_cast<const float4*>(base + j * 4096);
    float s[8];
    #pragma unroll
    for (int j = 0; j < 8; ++j) s[j] = (v[j].x + v[j].y) + (v[j].z + v[j].w);
    #pragma unroll
    for (int m = 32; m >= 1; m >>= 1) {
        #pragma unroll
        for (int j = 0; j < 8; ++j) s[j] += __shfl_xor(s[j], m, 64);
    }
    float r = s[0];
    r = (lane == 1) ? s[1] : r; r = (lane == 2) ? s[2] : r;
    r = (lane == 3) ? s[3] : r; r = (lane == 4) ? s[4] : r;
    r = (lane == 5) ? s[5] : r; r = (lane == 6) ? s[6] : r;
    r = (lane == 7) ? s[7] : r;
    if (lane < 8) y[wave * 8 + lane] = r * (1.0f / 256.0f);
}

__global__ void __launch_bounds__(256, 1) k_fc1(const float* __restrict__ w1,
                                                const float* __restrict__ y,
                                                float* __restrict__ h) {
    __shared__ float ys[B_ * C_];
    int tid = threadIdx.x, wib = tid >> 6, lane = tid & 63;
    int r0 = blockIdx.x * 8 + wib * 2;
    const float4* wr0 = reinterpret_cast<const float4*>(w1) + (size_t)r0 * 512;
    const float4* wr1 = wr0 + 512;
    float4 wA[8], wB[8];
    #pragma unroll
    for (int i = 0; i < 8; ++i) wA[i] = wr0[i * 64 + lane];
    #pragma unroll
    for (int i = 0; i < 8; ++i) wB[i] = wr1[i * 64 + lane];
    const float4* ysrc = reinterpret_cast<const float4*>(y);
    float4* ydst = reinterpret_cast<float4*>(ys);
    #pragma unroll 8
    for (int i = 0; i < 32; ++i) ydst[tid + 256 * i] = ysrc[tid + 256 * i];
    __syncthreads();
    float acc0[16], acc1[16];
    #pragma unroll
    for (int b = 0; b < 16; ++b) { acc0[b] = 0.f; acc1[b] = 0.f; }
    #pragma unroll
    for (int i = 0; i < 8; ++i) {
        const float4* yrow = reinterpret_cast<const float4*>(ys) + i * 64 + lane;
        #pragma unroll
        for (int b = 0; b < 16; ++b) {
            float4 v = yrow[b * 512];
            acc0[b] += wA[i].x * v.x + wA[i].y * v.y + wA[i].z * v.z + wA[i].w * v.w;
            acc1[b] += wB[i].x * v.x + wB[i].y * v.y + wB[i].z * v.z + wB[i].w * v.w;
        }
    }
    #pragma unroll
    for (int b = 0; b < 16; ++b) {
        #pragma unroll
        for (int m = 32; m >= 1; m >>= 1) {
            acc0[b] += __shfl_xor(acc0[b], m, 64);
            acc1[b] += __shfl_xor(acc1[b], m, 64);
        }
    }
    float v0 = acc0[0], v1 = acc1[0];
    #pragma unroll
    for (int b = 1; b < 16; ++b) {
        v0 = (lane == b) ? acc0[b] : v0;
        v1 = (lane == b) ? acc1[b] : v1;
    }
    if (lane < 16) {
        int p = r0 >> 7, k = r0 & 127;
        h[(p * B_ + lane) * CR_ + k]     = fmaxf(v0, 0.f);
        h[(p * B_ + lane) * CR_ + k + 1] = fmaxf(v1, 0.f);
    }
}

__global__ void __launch_bounds__(256) k_fc2(const float* __restrict__ w2,
                                             const float* __restrict__ h,
                                             float* __restrict__ out) {
    __shared__ float hs[B_ * CR_];
    int wib = threadIdx.x >> 6;
    int wid = blockIdx.x * 4 + wib;
    int lane = threadIdx.x & 63;
    int p = wid >> 7, c0 = (wid & 127) << 4;
    int row = lane >> 2, q = lane & 3;
    const float4* hsrc = reinterpret_cast<const float4*>(h + (size_t)p * B_ * CR_);
    float4* hdst = reinterpret_cast<float4*>(hs);
    #pragma unroll
    for (int i = 0; i < 2; ++i) hdst[threadIdx.x + i * 256] = hsrc[threadIdx.x + i * 256];
    __syncthreads();
    const float4* wr = reinterpret_cast<const float4*>(w2)
                     + ((size_t)p * C_ + c0 + row) * (CR_ / 4);
    float4 wv[8];
    #pragma unroll
    for (int j = 0; j < 8; ++j) wv[j] = wr[q + 4 * j];
    const float4* hv = reinterpret_cast<const float4*>(hs);
    float acc[16];
    #pragma unroll
    for (int b = 0; b < 16; ++b) acc[b] = 0.f;
    #pragma unroll
    for (int j = 0; j < 8; ++j) {
        #pragma unroll
        for (int b = 0; b < 16; ++b) {
            float4 h4 = hv[b * 32 + q + 4 * j];
            acc[b] += wv[j].x * h4.x + wv[j].y * h4.y + wv[j].z * h4.z + wv[j].w * h4.w;
        }
    }
    #pragma unroll
    for (int b = 0; b < 16; ++b) {
        acc[b] += __shfl_xor(acc[b], 1, 64);
        acc[b] += __shfl_xor(acc[b], 2, 64);
    }
    #pragma unroll
    for (int i = 0; i < 4; ++i) {
        float v = acc[i];
        v = (q == 1) ? acc[4 + i] : v;
        v = (q == 2) ? acc[8 + i] : v;
        v = (q == 3) ? acc[12 + i] : v;
        int b = q * 4 + i;
        out[(((size_t)p * B_ + b) << 11) + c0 + row] = 1.0f / (1.0f + expf(-v));
    }
}

extern "C" void kernel_launch(void* const* d_in, const int* in_sizes, int n_in,
                              void* d_out, int out_size, void* d_ws, size_t ws_size,
                              hipStream_t stream) {
    const float* x  = (const float*)d_in[0];
    const float* w1 = (const float*)d_in[1];
    const float* w2 = (const float*)d_in[2];
    float* out = (float*)d_out;
    float* y  = (float*)d_ws;                 // 32768 floats
    float* h2 = y + B_ * C_;                  // 32768 floats (sliced layout)
    unsigned* bars = (unsigned*)((char*)d_ws + 2 * B_ * C_ * sizeof(float));

    // Zero barrier counters each launch (graph-capturable, deterministic).
    hipMemsetAsync(bars, 0, 256, stream);

    void* args[] = { (void*)&x, (void*)&w1, (void*)&w2, (void*)&out,
                     (void*)&y, (void*)&h2, (void*)&bars };
    hipError_t err = hipLaunchCooperativeKernel((const void*)k_fused,
                                                dim3(256), dim3(512),
                                                args, 0, stream);
    if (err != hipSuccess) {
        // Fallback: R7 3-kernel path.
        k_mean<<<(B_ * C_ / 8) / 4, 256, 0, stream>>>(x, y);
        k_fc1<<<256, 256, 0, stream>>>(w1, y, (float*)h2);
        k_fc2<<<(P_ * C_ / 16) / 4, 256, 0, stream>>>(w2, (float*)h2, out);
    }
}

// Round 9
// 73.551 us; speedup vs baseline: 1.2456x; 1.2456x over previous
//
#include <hip/hip_runtime.h>
#include <math.h>

#define B_  16
#define C_  2048
#define P_  16
#define CR_ 128

// ---------------------------------------------------------------------------
// Grid barrier (relaxed spin + single acquire fence). Counters zeroed via
// hipMemsetAsync before each launch. Co-residency: grid=256=#CUs, 1 block/CU
// guaranteed by launch_bounds+LDS, exclusive GPU -> all blocks dispatch at
// once; spin cannot deadlock. (R8 A/B: this kernel under cooperative launch
// ran 91.6us; this round launches it as a REGULAR kernel, nothing else
// changed.)
// ---------------------------------------------------------------------------
__device__ __forceinline__ void gbar(unsigned* ctr, unsigned nblk) {
    __syncthreads();
    if (threadIdx.x == 0) {
        __hip_atomic_fetch_add(ctr, 1u, __ATOMIC_RELEASE, __HIP_MEMORY_SCOPE_AGENT);
        while (__hip_atomic_load(ctr, __ATOMIC_RELAXED, __HIP_MEMORY_SCOPE_AGENT) < nblk)
            __builtin_amdgcn_s_sleep(2);
        __builtin_amdgcn_fence(__ATOMIC_ACQUIRE, "agent");
    }
    __syncthreads();
}

// ===================== Fused kernel (body identical to R8) =====================
// grid = 256 blocks x 512 threads, 1 block/CU, 64 KiB LDS.
// P1: patch means -> y.   [W1 loads issued]  gbar.
// P2: fc1+relu -> h2 (block-exclusive 512B regions).  [W2 loads issued]  gbar.
// P3: fc2+sigmoid -> out.
__global__ void __launch_bounds__(512, 2) k_fused(
    const float* __restrict__ x, const float* __restrict__ w1,
    const float* __restrict__ w2, float* __restrict__ out,
    float* __restrict__ y, float* __restrict__ h2, unsigned* __restrict__ bars)
{
    __shared__ float smem[16 * 1024];                 // 64 KiB
    float4* sm4 = reinterpret_cast<float4*>(smem);
    const int tid  = threadIdx.x;
    const int wib  = tid >> 6;
    const int lane = tid & 63;
    const int bid  = blockIdx.x;

    // ---------- Phase 1: y[b][c] = mean of x[b,c,16:32,16:32] ----------
    {
        const int wid = bid * 8 + wib;                // [0,2048), 16 patches/wave
        const int row = lane >> 2, col = (lane & 3) * 4;
        const float* base = x + (size_t)wid * 16 * 4096 + (16 * 64 + 16)
                          + row * 64 + col;
        #pragma unroll
        for (int g = 0; g < 2; ++g) {
            float s[8];
            #pragma unroll
            for (int j = 0; j < 8; ++j) {
                float4 v = *reinterpret_cast<const float4*>(base + (g * 8 + j) * 4096);
                s[j] = (v.x + v.y) + (v.z + v.w);
            }
            #pragma unroll
            for (int j = 0; j < 8; ++j) {
                #pragma unroll
                for (int m = 32; m >= 1; m >>= 1) s[j] += __shfl_xor(s[j], m, 64);
            }
            float v = s[0];
            v = (lane == 1) ? s[1] : v;
            v = (lane == 2) ? s[2] : v;
            v = (lane == 3) ? s[3] : v;
            v = (lane == 4) ? s[4] : v;
            v = (lane == 5) ? s[5] : v;
            v = (lane == 6) ? s[6] : v;
            v = (lane == 7) ? s[7] : v;
            if (lane < 8) y[wid * 16 + g * 8 + lane] = v * (1.0f / 256.0f);
        }
    }

    // ---------- Phase 2 W1 prefetch: issue BEFORE the barrier ----------
    const bool work = (wib < 4);                      // 4 working waves/block
    const int r0 = (bid * 4 + wib) * 2;               // rows r0, r0+1 (same p)
    const float4* w1v = reinterpret_cast<const float4*>(w1);
    const float4* wr0 = w1v + (size_t)r0 * 512;
    const float4* wr1 = wr0 + 512;
    float4 wA[8], wB[8];
    if (work) {
        #pragma unroll
        for (int i = 0; i < 8; ++i) wA[i] = wr0[i * 64 + lane];
        #pragma unroll
        for (int i = 0; i < 8; ++i) wB[i] = wr1[i * 64 + lane];
    }

    gbar(&bars[0], 256u);

    // ---------- Phase 2: h2 = relu(W1 . y) ----------
    {
        const float4* yv = reinterpret_cast<const float4*>(y);

        float acc0[16], acc1[16];
        #pragma unroll
        for (int b = 0; b < 16; ++b) { acc0[b] = 0.f; acc1[b] = 0.f; }

        #pragma unroll
        for (int pass = 0; pass < 2; ++pass) {
            // stage y[:, pass*1024 : +1024] as [16][256] float4
            #pragma unroll
            for (int i = 0; i < 8; ++i) {
                int f = i * 512 + tid;                // [0,4096)
                int b = f >> 8, c4 = f & 255;
                sm4[f] = yv[b * 512 + pass * 256 + c4];
            }
            __syncthreads();
            if (work) {
                #pragma unroll
                for (int il = 0; il < 4; ++il) {
                    float4 wa = wA[pass * 4 + il];
                    float4 wb = wB[pass * 4 + il];
                    #pragma unroll
                    for (int b = 0; b < 16; ++b) {
                        float4 v = sm4[b * 256 + il * 64 + lane];
                        acc0[b] += wa.x * v.x + wa.y * v.y + wa.z * v.z + wa.w * v.w;
                        acc1[b] += wb.x * v.x + wb.y * v.y + wb.z * v.z + wb.w * v.w;
                    }
                }
            }
            __syncthreads();
        }

        if (work) {
            #pragma unroll
            for (int b = 0; b < 16; ++b) {
                #pragma unroll
                for (int m = 32; m >= 1; m >>= 1) {
                    acc0[b] += __shfl_xor(acc0[b], m, 64);
                    acc1[b] += __shfl_xor(acc1[b], m, 64);
                }
            }
            float v0 = acc0[0], v1 = acc1[0];
            #pragma unroll
            for (int b = 1; b < 16; ++b) {
                v0 = (lane == b) ? acc0[b] : v0;
                v1 = (lane == b) ? acc1[b] : v1;
            }
            if (lane < 16) {
                // h2[p][m][b][k']: p=r0>>7, m=bid&15, b=lane, k'=2*wib (+1)
                const int p = r0 >> 7;
                const int idx = p * 2048 + (bid & 15) * 128 + lane * 8 + 2 * wib;
                h2[idx]     = fmaxf(v0, 0.f);
                h2[idx + 1] = fmaxf(v1, 0.f);
            }
        }
    }

    // ---------- Phase 3 W2 prefetch: issue BEFORE the barrier ----------
    const int p3p = bid >> 4;
    const int c0  = (bid & 15) * 128 + wib * 16;      // 16 c-rows per wave
    const int row3 = lane >> 2, q = lane & 3;
    const float4* wr = reinterpret_cast<const float4*>(w2)
                     + ((size_t)p3p * C_ + c0 + row3) * (CR_ / 4);
    float4 wv[8];
    #pragma unroll
    for (int j = 0; j < 8; ++j) wv[j] = wr[q + 4 * j];

    gbar(&bars[32], 256u);

    // ---------- Phase 3: out[p][b][c] = sigmoid(W2[p][c][:] . h[p][b][:]) ----------
    {
        const float4* hv = reinterpret_cast<const float4*>(h2);
        sm4[tid] = hv[p3p * 512 + tid];               // stage h2[p] (8 KiB)
        __syncthreads();

        float acc[16];
        #pragma unroll
        for (int b = 0; b < 16; ++b) acc[b] = 0.f;
        #pragma unroll
        for (int j = 0; j < 8; ++j) {
            const int k4 = q + 4 * j;                 // float4 index in k
            const int m  = k4 >> 1, kk = k4 & 1;      // h2 slice / half
            #pragma unroll
            for (int b = 0; b < 16; ++b) {
                float4 h4 = sm4[m * 32 + b * 2 + kk];
                acc[b] += wv[j].x * h4.x + wv[j].y * h4.y
                        + wv[j].z * h4.z + wv[j].w * h4.w;
            }
        }
        #pragma unroll
        for (int b = 0; b < 16; ++b) {
            acc[b] += __shfl_xor(acc[b], 1, 64);
            acc[b] += __shfl_xor(acc[b], 2, 64);
        }
        #pragma unroll
        for (int i = 0; i < 4; ++i) {
            float v = acc[i];
            v = (q == 1) ? acc[4 + i]  : v;
            v = (q == 2) ? acc[8 + i]  : v;
            v = (q == 3) ? acc[12 + i] : v;
            int b = q * 4 + i;
            out[(((size_t)p3p * B_ + b) << 11) + c0 + row3] = 1.0f / (1.0f + expf(-v));
        }
    }
}

extern "C" void kernel_launch(void* const* d_in, const int* in_sizes, int n_in,
                              void* d_out, int out_size, void* d_ws, size_t ws_size,
                              hipStream_t stream) {
    const float* x  = (const float*)d_in[0];
    const float* w1 = (const float*)d_in[1];
    const float* w2 = (const float*)d_in[2];
    float* out = (float*)d_out;
    float* y  = (float*)d_ws;                 // 32768 floats
    float* h2 = y + B_ * C_;                  // 32768 floats (sliced layout)
    unsigned* bars = (unsigned*)((char*)d_ws + 2 * B_ * C_ * sizeof(float));

    // Zero barrier counters each launch (graph-capturable, deterministic).
    hipMemsetAsync(bars, 0, 256, stream);

    // REGULAR launch (R8 used hipLaunchCooperativeKernel with identical body).
    k_fused<<<256, 512, 0, stream>>>(x, w1, w2, out, y, h2, bars);
}

// Round 10
// 71.242 us; speedup vs baseline: 1.2859x; 1.0324x over previous
//
#include <hip/hip_runtime.h>
#include <math.h>

#define B_  16
#define C_  2048
#define P_  16
#define CR_ 128

// ---------------------------------------------------------------------------
// Grid barrier (relaxed spin + single acquire fence). Counters zeroed via
// hipMemsetAsync before each launch. Co-residency: grid=256=#CUs, 1 block/CU
// guaranteed by launch_bounds+LDS, exclusive GPU -> all blocks dispatch at
// once; spin cannot deadlock.
// ---------------------------------------------------------------------------
__device__ __forceinline__ void gbar(unsigned* ctr, unsigned nblk) {
    __syncthreads();
    if (threadIdx.x == 0) {
        __hip_atomic_fetch_add(ctr, 1u, __ATOMIC_RELEASE, __HIP_MEMORY_SCOPE_AGENT);
        while (__hip_atomic_load(ctr, __ATOMIC_RELAXED, __HIP_MEMORY_SCOPE_AGENT) < nblk)
            __builtin_amdgcn_s_sleep(2);
        __builtin_amdgcn_fence(__ATOMIC_ACQUIRE, "agent");
    }
    __syncthreads();
}

// ===================== Fused kernel =====================
// grid = 256 blocks x 512 threads, 1 block/CU, 64 KiB LDS.
// P1: patch means -> y  (ALL 16 loads in flight per wave: 128 lines/CU).
// [W1 prefetch]  gbar.  P2: fc1+relu -> h2.  [W2 prefetch]  gbar.
// P3: fc2+sigmoid -> out.
__global__ void __launch_bounds__(512, 2) k_fused(
    const float* __restrict__ x, const float* __restrict__ w1,
    const float* __restrict__ w2, float* __restrict__ out,
    float* __restrict__ y, float* __restrict__ h2, unsigned* __restrict__ bars)
{
    __shared__ float smem[16 * 1024];                 // 64 KiB
    float4* sm4 = reinterpret_cast<float4*>(smem);
    const int tid  = threadIdx.x;
    const int wib  = tid >> 6;
    const int lane = tid & 63;
    const int bid  = blockIdx.x;

    // ---------- Phase 1: y[b][c] = mean of x[b,c,16:32,16:32] ----------
    // 16 patches per wave, ALL loads issued before any reduction (ILP=16).
    {
        const int wid = bid * 8 + wib;                // [0,2048)
        const int row = lane >> 2, col = (lane & 3) * 4;
        const float* base = x + (size_t)wid * 16 * 4096 + (16 * 64 + 16)
                          + row * 64 + col;
        float4 v[16];
        #pragma unroll
        for (int j = 0; j < 16; ++j)
            v[j] = *reinterpret_cast<const float4*>(base + j * 4096);

        float s[16];
        #pragma unroll
        for (int j = 0; j < 16; ++j) s[j] = (v[j].x + v[j].y) + (v[j].z + v[j].w);

        #pragma unroll
        for (int m = 32; m >= 1; m >>= 1) {
            #pragma unroll
            for (int j = 0; j < 16; ++j) s[j] += __shfl_xor(s[j], m, 64);
        }

        float r = s[0];                               // static select (rule #20)
        #pragma unroll
        for (int j = 1; j < 16; ++j) r = (lane == j) ? s[j] : r;
        if (lane < 16) y[wid * 16 + lane] = r * (1.0f / 256.0f);
    }

    // ---------- Phase 2 W1 prefetch: issue BEFORE the barrier ----------
    const bool work = (wib < 4);                      // 4 working waves/block
    const int r0 = (bid * 4 + wib) * 2;               // rows r0, r0+1 (same p)
    const float4* w1v = reinterpret_cast<const float4*>(w1);
    const float4* wr0 = w1v + (size_t)r0 * 512;
    const float4* wr1 = wr0 + 512;
    float4 wA[8], wB[8];
    if (work) {
        #pragma unroll
        for (int i = 0; i < 8; ++i) wA[i] = wr0[i * 64 + lane];
        #pragma unroll
        for (int i = 0; i < 8; ++i) wB[i] = wr1[i * 64 + lane];
    }

    gbar(&bars[0], 256u);

    // ---------- Phase 2: h2 = relu(W1 . y) ----------
    {
        const float4* yv = reinterpret_cast<const float4*>(y);

        float acc0[16], acc1[16];
        #pragma unroll
        for (int b = 0; b < 16; ++b) { acc0[b] = 0.f; acc1[b] = 0.f; }

        #pragma unroll
        for (int pass = 0; pass < 2; ++pass) {
            // stage y[:, pass*1024 : +1024] as [16][256] float4
            #pragma unroll
            for (int i = 0; i < 8; ++i) {
                int f = i * 512 + tid;                // [0,4096)
                int b = f >> 8, c4 = f & 255;
                sm4[f] = yv[b * 512 + pass * 256 + c4];
            }
            __syncthreads();
            if (work) {
                #pragma unroll
                for (int il = 0; il < 4; ++il) {
                    float4 wa = wA[pass * 4 + il];
                    float4 wb = wB[pass * 4 + il];
                    #pragma unroll
                    for (int b = 0; b < 16; ++b) {
                        float4 v = sm4[b * 256 + il * 64 + lane];
                        acc0[b] += wa.x * v.x + wa.y * v.y + wa.z * v.z + wa.w * v.w;
                        acc1[b] += wb.x * v.x + wb.y * v.y + wb.z * v.z + wb.w * v.w;
                    }
                }
            }
            __syncthreads();
        }

        if (work) {
            #pragma unroll
            for (int b = 0; b < 16; ++b) {
                #pragma unroll
                for (int m = 32; m >= 1; m >>= 1) {
                    acc0[b] += __shfl_xor(acc0[b], m, 64);
                    acc1[b] += __shfl_xor(acc1[b], m, 64);
                }
            }
            float v0 = acc0[0], v1 = acc1[0];
            #pragma unroll
            for (int b = 1; b < 16; ++b) {
                v0 = (lane == b) ? acc0[b] : v0;
                v1 = (lane == b) ? acc1[b] : v1;
            }
            if (lane < 16) {
                // h2[p][m][b][k']: p=r0>>7, m=bid&15, b=lane, k'=2*wib (+1)
                const int p = r0 >> 7;
                const int idx = p * 2048 + (bid & 15) * 128 + lane * 8 + 2 * wib;
                h2[idx]     = fmaxf(v0, 0.f);
                h2[idx + 1] = fmaxf(v1, 0.f);
            }
        }
    }

    // ---------- Phase 3 W2 prefetch: issue BEFORE the barrier ----------
    const int p3p = bid >> 4;
    const int c0  = (bid & 15) * 128 + wib * 16;      // 16 c-rows per wave
    const int row3 = lane >> 2, q = lane & 3;
    const float4* wr = reinterpret_cast<const float4*>(w2)
                     + ((size_t)p3p * C_ + c0 + row3) * (CR_ / 4);
    float4 wv[8];
    #pragma unroll
    for (int j = 0; j < 8; ++j) wv[j] = wr[q + 4 * j];

    gbar(&bars[32], 256u);

    // ---------- Phase 3: out[p][b][c] = sigmoid(W2[p][c][:] . h[p][b][:]) ----------
    {
        const float4* hv = reinterpret_cast<const float4*>(h2);
        sm4[tid] = hv[p3p * 512 + tid];               // stage h2[p] (8 KiB)
        __syncthreads();

        float acc[16];
        #pragma unroll
        for (int b = 0; b < 16; ++b) acc[b] = 0.f;
        #pragma unroll
        for (int j = 0; j < 8; ++j) {
            const int k4 = q + 4 * j;                 // float4 index in k
            const int m  = k4 >> 1, kk = k4 & 1;      // h2 slice / half
            #pragma unroll
            for (int b = 0; b < 16; ++b) {
                float4 h4 = sm4[m * 32 + b * 2 + kk];
                acc[b] += wv[j].x * h4.x + wv[j].y * h4.y
                        + wv[j].z * h4.z + wv[j].w * h4.w;
            }
        }
        #pragma unroll
        for (int b = 0; b < 16; ++b) {
            acc[b] += __shfl_xor(acc[b], 1, 64);
            acc[b] += __shfl_xor(acc[b], 2, 64);
        }
        #pragma unroll
        for (int i = 0; i < 4; ++i) {
            float v = acc[i];
            v = (q == 1) ? acc[4 + i]  : v;
            v = (q == 2) ? acc[8 + i]  : v;
            v = (q == 3) ? acc[12 + i] : v;
            int b = q * 4 + i;
            out[(((size_t)p3p * B_ + b) << 11) + c0 + row3] = 1.0f / (1.0f + expf(-v));
        }
    }
}

extern "C" void kernel_launch(void* const* d_in, const int* in_sizes, int n_in,
                              void* d_out, int out_size, void* d_ws, size_t ws_size,
                              hipStream_t stream) {
    const float* x  = (const float*)d_in[0];
    const float* w1 = (const float*)d_in[1];
    const float* w2 = (const float*)d_in[2];
    float* out = (float*)d_out;
    float* y  = (float*)d_ws;                 // 32768 floats
    float* h2 = y + B_ * C_;                  // 32768 floats (sliced layout)
    unsigned* bars = (unsigned*)((char*)d_ws + 2 * B_ * C_ * sizeof(float));

    // Zero barrier counters each launch (graph-capturable, deterministic).
    hipMemsetAsync(bars, 0, 256, stream);

    k_fused<<<256, 512, 0, stream>>>(x, w1, w2, out, y, h2, bars);
}

// Round 11
// 38.883 us; speedup vs baseline: 2.3561x; 1.8322x over previous
//
#include <hip/hip_runtime.h>
#include <math.h>

#define B_  16
#define C_  2048
#define H_  64
#define W_  64
#define P_  16
#define CR_ 128
#define PS_ 16

// R4 configuration (best measured: 39.0 us). Fusion arc (R5-R10) proved
// grid-wide in-kernel handoff costs more than kernel boundaries on 8-XCD
// MI355X (~15us/barrier fence storm vs ~5-7us/boundary). 3-kernel path:
//   k_mean: 64 MiB forced fetch (64B useful per 128B line) ~ 11-16 us
//   k_fc1:  W1 16 MiB, y staged in LDS                      ~ 3 us
//   k_fc2:  W2 16 MiB coalesced-once                        ~ 3 us

// Kernel 1: y[b][c] = mean of x[b,c,16:32,16:32]. One wave per 4 patches.
__global__ void k_mean(const float* __restrict__ x, float* __restrict__ y) {
    int wave = blockIdx.x * (blockDim.x >> 6) + (threadIdx.x >> 6); // [0, B*C/4)
    int lane = threadIdx.x & 63;
    int row = lane >> 2;            // 0..15
    int col = (lane & 3) * 4;       // 0,4,8,12
    const float* base = x + (size_t)wave * 4 * (H_ * W_) + PS_ * W_ + PS_
                      + row * W_ + col;
    float4 v0 = *reinterpret_cast<const float4*>(base);
    float4 v1 = *reinterpret_cast<const float4*>(base + H_ * W_);
    float4 v2 = *reinterpret_cast<const float4*>(base + 2 * H_ * W_);
    float4 v3 = *reinterpret_cast<const float4*>(base + 3 * H_ * W_);
    float s0 = v0.x + v0.y + v0.z + v0.w;
    float s1 = v1.x + v1.y + v1.z + v1.w;
    float s2 = v2.x + v2.y + v2.z + v2.w;
    float s3 = v3.x + v3.y + v3.z + v3.w;
    #pragma unroll
    for (int m = 32; m >= 1; m >>= 1) {
        s0 += __shfl_xor(s0, m, 64);
        s1 += __shfl_xor(s1, m, 64);
        s2 += __shfl_xor(s2, m, 64);
        s3 += __shfl_xor(s3, m, 64);
    }
    float v = s0;                    // static select (rule #20)
    v = (lane == 1) ? s1 : v;
    v = (lane == 2) ? s2 : v;
    v = (lane == 3) ? s3 : v;
    if (lane < 4) y[wave * 4 + lane] = v * (1.0f / 256.0f);
}

// Kernel 2: h[p][b][k] = relu(sum_c W1[p][k][c] * y[b][c]).
// Grid = 256 blocks (1/CU). Block stages ALL of y (128 KiB) into LDS once,
// then handles 8 (p,k) rows: 2 rows per wave, W1 register-prefetched across
// the 8 c-chunks so HBM latency hides under the FMA+LDS phase.
__global__ void __launch_bounds__(256) k_fc1(const float* __restrict__ w1,
                                             const float* __restrict__ y,
                                             float* __restrict__ h) {
    __shared__ float ys[B_ * C_];                 // 128 KiB
    int tid  = threadIdx.x;
    int wib  = tid >> 6;
    int lane = tid & 63;

    const float4* ysrc = reinterpret_cast<const float4*>(y);
    float4* ydst = reinterpret_cast<float4*>(ys);
    #pragma unroll 8
    for (int i = 0; i < 32; ++i)
        ydst[tid + 256 * i] = ysrc[tid + 256 * i];
    __syncthreads();

    int r0 = blockIdx.x * 8 + wib * 2;            // even row id; r0+1 same p
    const float4* wr0 = reinterpret_cast<const float4*>(w1) + (size_t)r0 * (C_ / 4);
    const float4* wr1 = wr0 + (C_ / 4);

    float acc0[B_], acc1[B_];
    #pragma unroll
    for (int b = 0; b < B_; ++b) { acc0[b] = 0.0f; acc1[b] = 0.0f; }

    float4 pa = wr0[lane];
    float4 pb = wr1[lane];
    #pragma unroll
    for (int i = 0; i < 8; ++i) {
        float4 wa = pa, wb = pb;
        if (i < 7) { pa = wr0[(i + 1) * 64 + lane]; pb = wr1[(i + 1) * 64 + lane]; }
        const float4* yrow = reinterpret_cast<const float4*>(ys) + i * 64 + lane;
        #pragma unroll
        for (int b = 0; b < B_; ++b) {
            float4 v = yrow[b * (C_ / 4)];
            acc0[b] += wa.x * v.x + wa.y * v.y + wa.z * v.z + wa.w * v.w;
            acc1[b] += wb.x * v.x + wb.y * v.y + wb.z * v.z + wb.w * v.w;
        }
    }

    #pragma unroll
    for (int b = 0; b < B_; ++b) {
        #pragma unroll
        for (int m = 32; m >= 1; m >>= 1) {
            acc0[b] += __shfl_xor(acc0[b], m, 64);
            acc1[b] += __shfl_xor(acc1[b], m, 64);
        }
    }

    float v0 = acc0[0], v1 = acc1[0];
    #pragma unroll
    for (int b = 1; b < B_; ++b) {
        v0 = (lane == b) ? acc0[b] : v0;
        v1 = (lane == b) ? acc1[b] : v1;
    }
    if (lane < B_) {
        int p = r0 >> 7, k = r0 & 127;
        h[(p * B_ + lane) * CR_ + k]     = fmaxf(v0, 0.0f);
        h[(p * B_ + lane) * CR_ + k + 1] = fmaxf(v1, 0.0f);
    }
}

// Kernel 3 (wave-cooperative): out[p][b][c] = sigmoid(sum_k W2[p][c][k] * h[p][b][k]).
// Wave = (p, 16 consecutive c rows); W2 read coalesced exactly once; h[p] in LDS.
__global__ void __launch_bounds__(256) k_fc2(const float* __restrict__ w2,
                                             const float* __restrict__ h,
                                             float* __restrict__ out) {
    __shared__ float hs[B_ * CR_];                // 8 KiB

    int wib  = threadIdx.x >> 6;
    int wid  = blockIdx.x * 4 + wib;              // [0, 2048)
    int lane = threadIdx.x & 63;
    int p  = wid >> 7;
    int c0 = (wid & 127) << 4;
    int row = lane >> 2;
    int q   = lane & 3;

    const float4* hsrc = reinterpret_cast<const float4*>(h + (size_t)p * B_ * CR_);
    float4* hdst = reinterpret_cast<float4*>(hs);
    #pragma unroll
    for (int i = 0; i < 2; ++i)
        hdst[threadIdx.x + i * 256] = hsrc[threadIdx.x + i * 256];
    __syncthreads();

    const float4* wr = reinterpret_cast<const float4*>(w2)
                     + ((size_t)p * C_ + c0 + row) * (CR_ / 4);
    const float4* hv = reinterpret_cast<const float4*>(hs);

    float acc[B_];
    #pragma unroll
    for (int b = 0; b < B_; ++b) acc[b] = 0.0f;

    #pragma unroll
    for (int j = 0; j < 8; ++j) {
        float4 w4 = wr[q + 4 * j];
        #pragma unroll
        for (int b = 0; b < B_; ++b) {
            float4 h4 = hv[b * (CR_ / 4) + q + 4 * j];
            acc[b] += w4.x * h4.x + w4.y * h4.y + w4.z * h4.z + w4.w * h4.w;
        }
    }

    #pragma unroll
    for (int b = 0; b < B_; ++b) {
        acc[b] += __shfl_xor(acc[b], 1, 64);
        acc[b] += __shfl_xor(acc[b], 2, 64);
    }

    #pragma unroll
    for (int i = 0; i < 4; ++i) {
        float v = acc[i];
        v = (q == 1) ? acc[4 + i]  : v;
        v = (q == 2) ? acc[8 + i]  : v;
        v = (q == 3) ? acc[12 + i] : v;
        int b = q * 4 + i;
        out[(((size_t)p * B_ + b) << 11) + c0 + row] = 1.0f / (1.0f + expf(-v));
    }
}

extern "C" void kernel_launch(void* const* d_in, const int* in_sizes, int n_in,
                              void* d_out, int out_size, void* d_ws, size_t ws_size,
                              hipStream_t stream) {
    const float* x  = (const float*)d_in[0];
    const float* w1 = (const float*)d_in[1];
    const float* w2 = (const float*)d_in[2];
    float* out = (float*)d_out;
    float* y = (float*)d_ws;                 // B*C    = 32768 floats
    float* h = y + B_ * C_;                  // P*B*CR = 32768 floats

    // 1) patch mean: 8192 waves, 4 patches each
    k_mean<<<(B_ * C_ / 4) / 4, 256, 0, stream>>>(x, y);
    // 2) FC1 + relu: 256 blocks, y staged in LDS, 8 rows/block
    k_fc1<<<256, 256, 0, stream>>>(w1, y, h);
    // 3) FC2 + sigmoid: one wave per 16 c-rows = 2048 waves
    k_fc2<<<(P_ * C_ / 16) / 4, 256, 0, stream>>>(w2, h, out);
}